// Round 1
// baseline (1094.391 us; speedup 1.0000x reference)
//
#include <hip/hip_runtime.h>
#include <stdint.h>
#include <stddef.h>

// Problem dims (fixed by reference)
#define M_DIM 16384   // 8*2048
#define K_DIM 4096
#define N_DIM 4096

// GEMM tiling (m97 ladder structure)
#define BM 128
#define BN 128
#define BK 32

// Workspace layout
#define WS_SUM_OFF   0                    // double final |W| sum
#define WS_PART_OFF  256                  // 1024 double partials
#define WS_X_OFF     16384                // x as bf16: 16384*4096*2 = 134217728 B
#define WS_XBYTES    ((size_t)M_DIM * K_DIM * 2)
#define WS_W_OFF     (WS_X_OFF + WS_XBYTES)
#define WS_WBYTES    ((size_t)N_DIM * K_DIM * 2)
#define WS_NEEDED    (WS_W_OFF + WS_WBYTES)

typedef __attribute__((ext_vector_type(8))) short short8;   // 8 bf16 = 4 VGPRs
typedef __attribute__((ext_vector_type(4))) float floatx4;  // MFMA 16x16 accumulator

// float -> bf16 bits, round-to-nearest-even (matches default convert semantics)
__device__ __forceinline__ unsigned short f2bf_rne(float f) {
  unsigned u = __builtin_bit_cast(unsigned, f);
  u += 0x7FFFu + ((u >> 16) & 1u);
  return (unsigned short)(u >> 16);
}

__device__ __forceinline__ float get_scale(const double* __restrict__ sum) {
  // scale = max(mean(|W|), 1e-8); mean over 4096*4096 = 16777216 elements
  double m = *sum * (1.0 / 16777216.0);
  return (float)fmax(m, 1e-8);
}

// async global->LDS, 16 B per lane; LDS dest is wave-uniform base + lane*16
__device__ __forceinline__ void gload16(const void* g, void* l) {
  __builtin_amdgcn_global_load_lds(
      (const __attribute__((address_space(1))) void*)g,
      (__attribute__((address_space(3))) void*)l,
      16, 0, 0);
}

// ---------------------------------------------------------------------------
// Kernel 1: sum of |W| -> per-block double partials (deterministic)
// ---------------------------------------------------------------------------
__global__ void absmean_kernel(const float* __restrict__ W, double* __restrict__ partials) {
  const int n4 = (N_DIM * K_DIM) / 4;  // 4194304 float4s
  const float4* W4 = (const float4*)W;
  float s = 0.f;
  const int stride = gridDim.x * blockDim.x;
  for (int i = blockIdx.x * blockDim.x + threadIdx.x; i < n4; i += stride) {
    float4 v = W4[i];
    s += fabsf(v.x) + fabsf(v.y) + fabsf(v.z) + fabsf(v.w);
  }
#pragma unroll
  for (int off = 32; off > 0; off >>= 1) s += __shfl_down(s, off);
  __shared__ double bsum[4];
  if ((threadIdx.x & 63) == 0) bsum[threadIdx.x >> 6] = (double)s;
  __syncthreads();
  if (threadIdx.x == 0)
    partials[blockIdx.x] = bsum[0] + bsum[1] + bsum[2] + bsum[3];
}

// ---------------------------------------------------------------------------
// Kernel 2: reduce 1024 partials -> final double sum (deterministic)
// ---------------------------------------------------------------------------
__global__ void reduce2_kernel(const double* __restrict__ partials, double* __restrict__ sum) {
  double s = 0.0;
  for (int i = threadIdx.x; i < 1024; i += 256) s += partials[i];
#pragma unroll
  for (int off = 32; off > 0; off >>= 1) s += __shfl_down(s, off);
  __shared__ double wsum[4];
  if ((threadIdx.x & 63) == 0) wsum[threadIdx.x >> 6] = s;
  __syncthreads();
  if (threadIdx.x == 0) *sum = wsum[0] + wsum[1] + wsum[2] + wsum[3];
}

// ---------------------------------------------------------------------------
// Kernel 3: quantize W -> ternary {-1,0,1} stored as bf16 (exact in bf16)
// True fp32 division + rintf (half-even) to bit-match np round(w/scale).
// ---------------------------------------------------------------------------
__global__ void quantw_kernel(const float* __restrict__ W, const double* __restrict__ sum,
                              unsigned short* __restrict__ T) {
  const int n4 = (N_DIM * K_DIM) / 4;
  const float s = get_scale(sum);
  const float4* W4 = (const float4*)W;
  ushort4* T4 = (ushort4*)T;
  const int stride = gridDim.x * blockDim.x;
  for (int i = blockIdx.x * blockDim.x + threadIdx.x; i < n4; i += stride) {
    float4 v = W4[i];
    float q0 = fminf(fmaxf(rintf(v.x / s), -1.f), 1.f);
    float q1 = fminf(fmaxf(rintf(v.y / s), -1.f), 1.f);
    float q2 = fminf(fmaxf(rintf(v.z / s), -1.f), 1.f);
    float q3 = fminf(fmaxf(rintf(v.w / s), -1.f), 1.f);
    ushort4 o;
    o.x = f2bf_rne(q0); o.y = f2bf_rne(q1); o.z = f2bf_rne(q2); o.w = f2bf_rne(q3);
    T4[i] = o;
  }
}

// ---------------------------------------------------------------------------
// Kernel 4: convert x fp32 -> bf16
// ---------------------------------------------------------------------------
__global__ void xconv_kernel(const float* __restrict__ X, unsigned short* __restrict__ O) {
  const int n4 = (M_DIM * K_DIM) / 4;  // 16777216 float4s
  const float4* X4 = (const float4*)X;
  ushort4* O4 = (ushort4*)O;
  const int stride = gridDim.x * blockDim.x;
  for (int i = blockIdx.x * blockDim.x + threadIdx.x; i < n4; i += stride) {
    float4 v = X4[i];
    ushort4 o;
    o.x = f2bf_rne(v.x); o.y = f2bf_rne(v.y); o.z = f2bf_rne(v.z); o.w = f2bf_rne(v.w);
    O4[i] = o;
  }
}

// ---------------------------------------------------------------------------
// Kernel 5: GEMM  C[m,n] = s * sum_k A[m,k]*T[n,k] + bias[n]
// A: [M,K] bf16 (K-contiguous), T: [N,K] bf16 (K-contiguous, "B^T input")
// 128x128 block tile, BK=32, 4 waves each computing a 64x64 subtile via
// 4x4 grid of 16x16x32 bf16 MFMA; global_load_lds width-16 staging.
// ---------------------------------------------------------------------------
__global__ __launch_bounds__(256) void gemm_kernel(
    const unsigned short* __restrict__ A,
    const unsigned short* __restrict__ B,
    const float* __restrict__ bias,
    const double* __restrict__ sum,
    float* __restrict__ C) {
  __shared__ __align__(16) unsigned short sA[BM * BK];  // 8 KB, row-major [row][k]
  __shared__ __align__(16) unsigned short sB[BN * BK];  // 8 KB

  const int tid = threadIdx.x;
  const int w = tid >> 6;       // wave 0..3
  const int l = tid & 63;       // lane
  const int wm = w & 1;         // wave M half
  const int wn = w >> 1;        // wave N half
  const int blockM = blockIdx.y * BM;
  const int blockN = blockIdx.x * BN;

  // --- staging addresses (global_load_lds: lane i -> ldsbase + i*16) ---
  // round r in {0,1} covers rows [r*64, r*64+64); thread t stages 16 B:
  //   row = r*64 + w*16 + l/4, kcol = (l%4)*8  -> lds byte = r*4096 + t*16
  const int srow = w * 16 + (l >> 2);
  const int skcol = (l & 3) * 8;
  const unsigned short* pA0 = A + (size_t)(blockM + srow) * K_DIM + skcol;
  const unsigned short* pA1 = pA0 + (size_t)64 * K_DIM;
  const unsigned short* pB0 = B + (size_t)(blockN + srow) * K_DIM + skcol;
  const unsigned short* pB1 = pB0 + (size_t)64 * K_DIM;
  char* ldsA0 = (char*)sA + w * 1024;          // wave-uniform bases
  char* ldsA1 = (char*)sA + 4096 + w * 1024;
  char* ldsB0 = (char*)sB + w * 1024;
  char* ldsB1 = (char*)sB + 4096 + w * 1024;

  // --- fragment read offsets ---
  // A-frag (16x16x32): lane holds A[m = l&15][k = (l>>4)*8 + j], j=0..7
  // B-frag:            lane holds B[k = (l>>4)*8 + j][n = l&15]  (= W[n][k])
  const int arow = wm * 64 + (l & 15);
  const int brow = wn * 64 + (l & 15);
  const int kq = (l >> 4) * 8;

  floatx4 acc[4][4] = {};  // zero-init accumulators (AGPRs)

  for (int kt = 0; kt < K_DIM / BK; ++kt) {
    __syncthreads();  // previous iter's LDS reads done before overwrite
    gload16(pA0, ldsA0);
    gload16(pA1, ldsA1);
    gload16(pB0, ldsB0);
    gload16(pB1, ldsB1);
    pA0 += BK; pA1 += BK; pB0 += BK; pB1 += BK;
    __syncthreads();  // compiler drains vmcnt(0) before s_barrier

    short8 af[4], bf[4];
#pragma unroll
    for (int mi = 0; mi < 4; ++mi)
      af[mi] = *(const short8*)&sA[(arow + mi * 16) * BK + kq];
#pragma unroll
    for (int ni = 0; ni < 4; ++ni)
      bf[ni] = *(const short8*)&sB[(brow + ni * 16) * BK + kq];
#pragma unroll
    for (int mi = 0; mi < 4; ++mi)
#pragma unroll
      for (int ni = 0; ni < 4; ++ni)
        acc[mi][ni] = __builtin_amdgcn_mfma_f32_16x16x32_bf16(
            af[mi], bf[ni], acc[mi][ni], 0, 0, 0);
  }

  // --- epilogue: C = acc*scale + bias ---
  // C/D layout (verified m89/m91): col = l&15, row = (l>>4)*4 + reg
  const float s = get_scale(sum);
  const int col16 = l & 15;
  const int rquad = (l >> 4) * 4;
#pragma unroll
  for (int mi = 0; mi < 4; ++mi) {
#pragma unroll
    for (int ni = 0; ni < 4; ++ni) {
      const int col = blockN + wn * 64 + ni * 16 + col16;
      const float bv = bias[col];
      const int row0 = blockM + wm * 64 + mi * 16 + rquad;
#pragma unroll
      for (int r = 0; r < 4; ++r) {
        C[(size_t)(row0 + r) * N_DIM + col] = acc[mi][ni][r] * s + bv;
      }
    }
  }
}

// ---------------------------------------------------------------------------
extern "C" void kernel_launch(void* const* d_in, const int* in_sizes, int n_in,
                              void* d_out, int out_size, void* d_ws, size_t ws_size,
                              hipStream_t stream) {
  const float* x = (const float*)d_in[0];     // [8,2048,4096] fp32
  const float* wt = (const float*)d_in[1];    // [4096,4096] fp32
  const float* bias = (const float*)d_in[2];  // [4096] fp32
  float* out = (float*)d_out;                 // [8,2048,4096] fp32

  if (ws_size < WS_NEEDED) return;  // need ~160 MB scratch; bail visibly if absent

  double* sum = (double*)((char*)d_ws + WS_SUM_OFF);
  double* partials = (double*)((char*)d_ws + WS_PART_OFF);
  unsigned short* xb = (unsigned short*)((char*)d_ws + WS_X_OFF);
  unsigned short* wb = (unsigned short*)((char*)d_ws + WS_W_OFF);

  absmean_kernel<<<1024, 256, 0, stream>>>(wt, partials);
  reduce2_kernel<<<1, 256, 0, stream>>>(partials, sum);
  quantw_kernel<<<1024, 256, 0, stream>>>(wt, sum, wb);
  xconv_kernel<<<2048, 256, 0, stream>>>(x, xb);
  dim3 grid(N_DIM / BN, M_DIM / BM);  // x = n-blocks (share A panel), y = m-blocks
  gemm_kernel<<<grid, 256, 0, stream>>>(xb, wb, bias, sum, out);
}

// Round 2
// 1086.108 us; speedup vs baseline: 1.0076x; 1.0076x over previous
//
#include <hip/hip_runtime.h>
#include <stdint.h>
#include <stddef.h>

// Problem dims (fixed by reference)
#define M_DIM 16384   // 8*2048
#define K_DIM 4096
#define N_DIM 4096

// GEMM tiling (m97 ladder structure)
#define BM 128
#define BN 128
#define BK 32

// Workspace layout
#define WS_SUM_OFF   0                    // double final |W| sum
#define WS_PART_OFF  256                  // 1024 double partials
#define WS_X_OFF     16384                // x as bf16: 16384*4096*2 = 134217728 B
#define WS_XBYTES    ((size_t)M_DIM * K_DIM * 2)
#define WS_W_OFF     (WS_X_OFF + WS_XBYTES)
#define WS_WBYTES    ((size_t)N_DIM * K_DIM * 2)
#define WS_NEEDED    (WS_W_OFF + WS_WBYTES)

typedef __attribute__((ext_vector_type(8))) short short8;   // 8 bf16 = 4 VGPRs
typedef __attribute__((ext_vector_type(4))) float floatx4;  // MFMA 16x16 accumulator

// float -> bf16 bits, round-to-nearest-even
__device__ __forceinline__ unsigned short f2bf_rne(float f) {
  unsigned u = __builtin_bit_cast(unsigned, f);
  u += 0x7FFFu + ((u >> 16) & 1u);
  return (unsigned short)(u >> 16);
}

__device__ __forceinline__ float get_scale(const double* __restrict__ sum) {
  double m = *sum * (1.0 / 16777216.0);
  return (float)fmax(m, 1e-8);
}

// async global->LDS, 16 B per lane; LDS dest is wave-uniform base + lane*16
__device__ __forceinline__ void gload16(const void* g, void* l) {
  __builtin_amdgcn_global_load_lds(
      (const __attribute__((address_space(1))) void*)g,
      (__attribute__((address_space(3))) void*)l,
      16, 0, 0);
}

// ---------------------------------------------------------------------------
// Kernel 1 (fused): blocks [0,1024): sum|W| -> double partials (deterministic)
//                   blocks [1024,4096): convert x fp32 -> bf16
// ---------------------------------------------------------------------------
__global__ void prep_kernel(const float* __restrict__ W, double* __restrict__ partials,
                            const float* __restrict__ X, unsigned short* __restrict__ XO) {
  if (blockIdx.x < 1024) {
    const int n4 = (N_DIM * K_DIM) / 4;  // 4194304 float4s
    const float4* W4 = (const float4*)W;
    float s = 0.f;
    const int stride = 1024 * blockDim.x;
    for (int i = blockIdx.x * blockDim.x + threadIdx.x; i < n4; i += stride) {
      float4 v = W4[i];
      s += fabsf(v.x) + fabsf(v.y) + fabsf(v.z) + fabsf(v.w);
    }
#pragma unroll
    for (int off = 32; off > 0; off >>= 1) s += __shfl_down(s, off);
    __shared__ double bsum[4];
    if ((threadIdx.x & 63) == 0) bsum[threadIdx.x >> 6] = (double)s;
    __syncthreads();
    if (threadIdx.x == 0)
      partials[blockIdx.x] = bsum[0] + bsum[1] + bsum[2] + bsum[3];
  } else {
    const int n4 = (M_DIM * K_DIM) / 4;  // 16777216 float4s
    const float4* X4 = (const float4*)X;
    ushort4* O4 = (ushort4*)XO;
    const int nblk = 3072;
    const int stride = nblk * blockDim.x;
    for (int i = (blockIdx.x - 1024) * blockDim.x + threadIdx.x; i < n4; i += stride) {
      float4 v = X4[i];
      ushort4 o;
      o.x = f2bf_rne(v.x); o.y = f2bf_rne(v.y); o.z = f2bf_rne(v.z); o.w = f2bf_rne(v.w);
      O4[i] = o;
    }
  }
}

// ---------------------------------------------------------------------------
// Kernel 2: reduce 1024 partials -> final double sum (deterministic)
// ---------------------------------------------------------------------------
__global__ void reduce2_kernel(const double* __restrict__ partials, double* __restrict__ sum) {
  double s = 0.0;
  for (int i = threadIdx.x; i < 1024; i += 256) s += partials[i];
#pragma unroll
  for (int off = 32; off > 0; off >>= 1) s += __shfl_down(s, off);
  __shared__ double wsum[4];
  if ((threadIdx.x & 63) == 0) wsum[threadIdx.x >> 6] = s;
  __syncthreads();
  if (threadIdx.x == 0) *sum = wsum[0] + wsum[1] + wsum[2] + wsum[3];
}

// ---------------------------------------------------------------------------
// Kernel 3: quantize W -> ternary {-1,0,1} stored as bf16 (exact in bf16)
// ---------------------------------------------------------------------------
__global__ void quantw_kernel(const float* __restrict__ W, const double* __restrict__ sum,
                              unsigned short* __restrict__ T) {
  const int n4 = (N_DIM * K_DIM) / 4;
  const float s = get_scale(sum);
  const float4* W4 = (const float4*)W;
  ushort4* T4 = (ushort4*)T;
  const int stride = gridDim.x * blockDim.x;
  for (int i = blockIdx.x * blockDim.x + threadIdx.x; i < n4; i += stride) {
    float4 v = W4[i];
    float q0 = fminf(fmaxf(rintf(v.x / s), -1.f), 1.f);
    float q1 = fminf(fmaxf(rintf(v.y / s), -1.f), 1.f);
    float q2 = fminf(fmaxf(rintf(v.z / s), -1.f), 1.f);
    float q3 = fminf(fmaxf(rintf(v.w / s), -1.f), 1.f);
    ushort4 o;
    o.x = f2bf_rne(q0); o.y = f2bf_rne(q1); o.z = f2bf_rne(q2); o.w = f2bf_rne(q3);
    T4[i] = o;
  }
}

// ---------------------------------------------------------------------------
// Kernel 4: GEMM  C[m,n] = s * sum_k A[m,k]*T[n,k] + bias[n]
// XOR-swizzled LDS: 16B chunk kc of row r stored at physical chunk
// kc ^ ((r>>1)&3). Each 16-lane ds_read_b128 phase then covers all 32 banks
// at exactly 2 words/bank (HW minimum; 2-way is free per m136).
// ---------------------------------------------------------------------------
__global__ __launch_bounds__(256) void gemm_kernel(
    const unsigned short* __restrict__ A,
    const unsigned short* __restrict__ B,
    const float* __restrict__ bias,
    const double* __restrict__ sum,
    float* __restrict__ C) {
  __shared__ __align__(16) unsigned short sA[BM * BK];  // 8 KB
  __shared__ __align__(16) unsigned short sB[BN * BK];  // 8 KB

  const int tid = threadIdx.x;
  const int w = tid >> 6;       // wave 0..3
  const int l = tid & 63;       // lane
  const int wm = w & 1;         // wave M half
  const int wn = w >> 1;        // wave N half
  const int blockM = blockIdx.y * BM;
  const int blockN = blockIdx.x * BN;

  // --- staging (global_load_lds: thread t -> ldsbase + t*16, contiguous) ---
  // thread t stages LDS (row = t/4, phys chunk = t%4); with the XOR swizzle the
  // GLOBAL chunk it must fetch is kc = (t%4) ^ ((row>>1)&3) = (l&3)^((l>>3)&3).
  const int srow = w * 16 + (l >> 2);
  const int skc = ((l & 3) ^ ((l >> 3) & 3)) * 8;  // global k offset (shorts)
  const unsigned short* pA0 = A + (size_t)(blockM + srow) * K_DIM + skc;
  const unsigned short* pA1 = pA0 + (size_t)64 * K_DIM;
  const unsigned short* pB0 = B + (size_t)(blockN + srow) * K_DIM + skc;
  const unsigned short* pB1 = pB0 + (size_t)64 * K_DIM;
  char* ldsA0 = (char*)sA + w * 1024;
  char* ldsA1 = (char*)sA + 4096 + w * 1024;
  char* ldsB0 = (char*)sB + w * 1024;
  char* ldsB1 = (char*)sB + 4096 + w * 1024;

  // --- fragment read offsets (swizzled) ---
  // A-frag: lane holds A[m = l&15][k-chunk q = l>>4]; row = wm*64 + (l&15) + mi*16.
  // swizzle term ((row>>1)&3) = ((l>>1)&3) — invariant under mi*16 and wm*64,
  // so addresses stay linear in mi (no extra K-loop VALU).
  const int arow = wm * 64 + (l & 15);
  const int brow = wn * 64 + (l & 15);
  const int koff = (((l >> 4) ^ ((l >> 1) & 3))) * 8;  // swizzled chunk, in shorts

  floatx4 acc[4][4] = {};

  for (int kt = 0; kt < K_DIM / BK; ++kt) {
    __syncthreads();
    gload16(pA0, ldsA0);
    gload16(pA1, ldsA1);
    gload16(pB0, ldsB0);
    gload16(pB1, ldsB1);
    pA0 += BK; pA1 += BK; pB0 += BK; pB1 += BK;
    __syncthreads();

    short8 af[4], bf[4];
#pragma unroll
    for (int mi = 0; mi < 4; ++mi)
      af[mi] = *(const short8*)&sA[(arow + mi * 16) * BK + koff];
#pragma unroll
    for (int ni = 0; ni < 4; ++ni)
      bf[ni] = *(const short8*)&sB[(brow + ni * 16) * BK + koff];
#pragma unroll
    for (int mi = 0; mi < 4; ++mi)
#pragma unroll
      for (int ni = 0; ni < 4; ++ni)
        acc[mi][ni] = __builtin_amdgcn_mfma_f32_16x16x32_bf16(
            af[mi], bf[ni], acc[mi][ni], 0, 0, 0);
  }

  // --- epilogue: C = acc*scale + bias ---
  // C/D layout: col = l&15, row = (l>>4)*4 + reg
  const float s = get_scale(sum);
  const int col16 = l & 15;
  const int rquad = (l >> 4) * 4;
#pragma unroll
  for (int mi = 0; mi < 4; ++mi) {
#pragma unroll
    for (int ni = 0; ni < 4; ++ni) {
      const int col = blockN + wn * 64 + ni * 16 + col16;
      const float bv = bias[col];
      const int row0 = blockM + wm * 64 + mi * 16 + rquad;
#pragma unroll
      for (int r = 0; r < 4; ++r) {
        C[(size_t)(row0 + r) * N_DIM + col] = acc[mi][ni][r] * s + bv;
      }
    }
  }
}

// ---------------------------------------------------------------------------
extern "C" void kernel_launch(void* const* d_in, const int* in_sizes, int n_in,
                              void* d_out, int out_size, void* d_ws, size_t ws_size,
                              hipStream_t stream) {
  const float* x = (const float*)d_in[0];     // [8,2048,4096] fp32
  const float* wt = (const float*)d_in[1];    // [4096,4096] fp32
  const float* bias = (const float*)d_in[2];  // [4096] fp32
  float* out = (float*)d_out;                 // [8,2048,4096] fp32

  if (ws_size < WS_NEEDED) return;

  double* sum = (double*)((char*)d_ws + WS_SUM_OFF);
  double* partials = (double*)((char*)d_ws + WS_PART_OFF);
  unsigned short* xb = (unsigned short*)((char*)d_ws + WS_X_OFF);
  unsigned short* wb = (unsigned short*)((char*)d_ws + WS_W_OFF);

  prep_kernel<<<4096, 256, 0, stream>>>(wt, partials, x, xb);
  reduce2_kernel<<<1, 256, 0, stream>>>(partials, sum);
  quantw_kernel<<<1024, 256, 0, stream>>>(wt, sum, wb);
  dim3 grid(N_DIM / BN, M_DIM / BM);
  gemm_kernel<<<grid, 256, 0, stream>>>(xb, wb, bias, sum, out);
}